// Round 7
// baseline (146.542 us; speedup 1.0000x reference)
//
#include <hip/hip_runtime.h>

#define B_DIM 4096
#define L_DIM 4096
#define SEGLEN 256
#define NSEG (L_DIM / SEGLEN)   // 16
#define WARM 512                // coupling window (proven exact)
#define CHUNK 32                // time steps per chunk (halved: triple-buffer fits)
#define LROW 32                 // LDS floats per row-chunk (linear, gll dest)

// Exact IEEE step (proven absmax 0): q = RN(u/20) via Markstein, compare off
// the dependent chain: u' = sp_prev ? I' : ((u - q) + I')
#define LIF_CORE(IIN)                         \
    float q0 = u * cdiv;                      \
    float rr = fmaf(-20.0f, q0, u);           \
    float q  = fmaf(rr, cdiv, q0);            \
    float a  = u - q;                         \
    float b  = a + (IIN);                     \
    u = sp ? (IIN) : b;                       \
    sp = (u >= 1.0f);

#define WARM_STEP(IIN) { LIF_CORE(IIN) }

#define FULL_STEP(IIN, SOUT)                  \
    {                                         \
        LIF_CORE(IIN)                         \
        float sf = sp ? 1.0f : 0.0f;          \
        cnt += sf;                            \
        seen = fmaxf(seen, sf);               \
        accS += cnt;                          \
        accF += seen;                         \
        (SOUT) = sf;                          \
    }

typedef const __attribute__((address_space(1))) void g_void;
typedef __attribute__((address_space(3))) void l_void;
__device__ __forceinline__ void gll16(const float* src, float* ldsbase) {
    // async global->LDS, 16B/lane; LDS dest = wave-uniform base + lane*16B
    __builtin_amdgcn_global_load_lds((g_void*)src, (l_void*)ldsbase, 16, 0, 0);
}

#define VMCNT(N)                                             \
    asm volatile("s_waitcnt vmcnt(" #N ")" ::: "memory");    \
    __builtin_amdgcn_sched_barrier(0);

// Fully decoupled waves (round-6 topology, proven clean traffic), now with
// DEPTH-2 prefetch: triple-buffered LDS (3 x 4KB/wave... 3 x 8KB? see below),
// CHUNK=32 so 3 bufs * 64rows*32fl*4B = 24KB/wave fit 2 waves/block (48KB).
// gll(c+2) is issued at iter c -> ~2 full iterations (~3k cyc) of slack
// before the wait for gll(c), taking L2/L3/HBM latency OFF the per-iter
// critical path that round 6 (depth-1, 1 wave/SIMD) fully exposed.
//
// Counted waits = exact "#ops younger than the last gll(c) instr" (8 gll
// per chunk, 8 stores per main chunk; vmcnt retires in issue order):
//   warm/first-main/last iter: 16   boundary / nch-2: 24   steady main: 32
// Never looser than exact -> no stale-LDS risk; store lifetime <= 3 iters
// (keeps round-6's clean write-back, WRITE_SIZE == output exactly).
//
// Swizzle (rule #21 both-sides): LDS slot (r,k) holds global float4-block
// (k-r)&7; per-lane gll/store source offset swz=((scol-srow)&7)*4 floats,
// transposed reads/writes use slot (j+lane)&7. 16-lane b128 phases touch
// each bank <=2x -> conflict-free (round 6 measured 0).
//
// XCD-local mapping: dispatch assigns XCD = blockIdx%8; rg=(b&7)*8+((b>>3)&7)
// pins all 8 seg-pair blocks of a rowgroup to ONE XCD -> warm re-reads hit
// the local L2 instead of die-level L3 (round 6: partner always remote).
__global__ __launch_bounds__(128, 1) void lif_kernel(const float* __restrict__ I,
                                                     float* __restrict__ out,
                                                     float* __restrict__ Cacc,
                                                     float* __restrict__ tsAcc,
                                                     int* __restrict__ firstAcc) {
    __shared__ __align__(16) float lds[2][3][64 * LROW];  // 2 waves x 3 x 8KB = 48KB
    const int wid = threadIdx.x >> 6;
    const int lane = threadIdx.x & 63;
    const int b = blockIdx.x;
    const int rg = (b & 7) * 8 + ((b >> 3) & 7);   // rowgroup, XCD-local
    const int sp = b >> 6;                         // segment pair
    const int seg = 2 * sp + wid;
    const int rowBase = rg * 64;
    const int t0 = seg * SEGLEN;
    const int start = (t0 > WARM) ? (t0 - WARM) : 0;
    const int nwarmCh = (t0 - start) / CHUNK;      // 0, 8, or 16
    const int nch = nwarmCh + SEGLEN / CHUNK;      // 8, 16, or 24

    const int srow = lane >> 3, scol = lane & 7;
    const int swz = ((scol - srow) & 7) << 2;      // float offset of swizzled block
    const float* gbase = I + (size_t)rowBase * L_DIM + start;

    float* bA = &lds[wid][0][0];   // chunk c
    float* bB = &lds[wid][1][0];   // chunk c+1
    float* bC = &lds[wid][2][0];   // chunk c+2 (gll target)

    const int row = rowBase + lane;
    float u = 0.f, cnt = 0.f, seen = 0.f, accS = 0.f, accF = 0.f;
    bool sp_ = false;
    const float cdiv = 0.05f;  // RN(1/20)
#define sp sp_

#define GLL_CHUNK(CC, DST)                                              \
    {                                                                   \
        const float* gsrc = gbase + (size_t)(CC) * CHUNK;               \
        _Pragma("unroll")                                               \
        for (int p = 0; p < 8; ++p)                                     \
            gll16(gsrc + (size_t)(8 * p + srow) * L_DIM + swz,          \
                  (DST) + p * 256);                                     \
    }

    // prologue: start the pipeline two chunks deep
    GLL_CHUNK(0, bA)
    GLL_CHUNK(1, bB)

    for (int c = 0; c < nch; ++c) {
        // 1. issue gll(c+2) (youngest; counted in the waits below)
        if (c + 2 < nch) GLL_CHUNK(c + 2, bC)

        // 2. wait until exactly gll(c) has landed in bA (phase-exact count)
        if (c <= nwarmCh || c == nch - 1) {
            VMCNT(16)
        } else if (c == nwarmCh + 1 || c == nch - 2) {
            VMCNT(24)
        } else {
            VMCNT(32)
        }

        // 3. transposed read: row-per-lane, swizzled slots
        float4 R[8];
#pragma unroll
        for (int j = 0; j < 8; ++j)
            R[j] = *(const float4*)&bA[lane * LROW + (((j + lane) & 7) << 2)];

        // 4. compute chunk c
        if (c < nwarmCh) {
#pragma unroll
            for (int j = 0; j < 8; ++j) {
                float4 iv = R[j];
                WARM_STEP(iv.x) WARM_STEP(iv.y) WARM_STEP(iv.z) WARM_STEP(iv.w)
            }
        } else {
            // spikes overwrite bA (input consumed into R; same-wave in-order LDS)
#pragma unroll
            for (int j = 0; j < 8; ++j) {
                float4 iv = R[j];
                float4 sv;
                FULL_STEP(iv.x, sv.x) FULL_STEP(iv.y, sv.y)
                FULL_STEP(iv.z, sv.z) FULL_STEP(iv.w, sv.w)
                *(float4*)&bA[lane * LROW + (((j + lane) & 7) << 2)] = sv;
            }
            // 5. coalesced spike store: linear LDS read -> swizzled global col
            float4 S[8];
#pragma unroll
            for (int p = 0; p < 8; ++p)
                S[p] = *(const float4*)&bA[p * 256 + (lane << 2)];
            float* og = out + (size_t)rowBase * L_DIM + t0 +
                        (size_t)(c - nwarmCh) * CHUNK;
#pragma unroll
            for (int p = 0; p < 8; ++p)
                *(float4*)(og + (size_t)(8 * p + srow) * L_DIM + swz) = S[p];
        }

        // 6. rotate buffers (pointer regs only -- no indexed array, no scratch)
        float* t = bA; bA = bB; bB = bC; bC = t;
    }

    // per-segment partials (exact integers < 2^24 -> float atomics exact)
    if (cnt > 0.f) {
        const int firstLocal = (int)((float)SEGLEN - accF);
        atomicMin(&firstAcc[row], t0 + firstLocal);
    }
    atomicAdd(&Cacc[row], cnt);
    atomicAdd(&tsAcc[row], fmaf((float)(t0 + SEGLEN), cnt, -accS));
#undef sp
#undef GLL_CHUNK
}

__global__ __launch_bounds__(256) void fin_kernel(const float* __restrict__ Cacc,
                                                  const float* __restrict__ tsAcc,
                                                  const int* __restrict__ firstAcc,
                                                  float* __restrict__ out) {
    int r = blockIdx.x * 256 + threadIdx.x;
    if (r < B_DIM) {
        // firstAcc initialized to 0x7F7F7F7F by memset; clamp restores the
        // exact no-spike identity L_DIM.
        int f = firstAcc[r];
        out[(size_t)B_DIM * L_DIM + r] = (float)(f > L_DIM ? L_DIM : f);
        out[(size_t)B_DIM * L_DIM + B_DIM + r] = tsAcc[r] / (Cacc[r] + 1e-6f);
    }
}

extern "C" void kernel_launch(void* const* d_in, const int* in_sizes, int n_in,
                              void* d_out, int out_size, void* d_ws, size_t ws_size,
                              hipStream_t stream) {
    const float* I = (const float*)d_in[0];
    float* out = (float*)d_out;
    float* wsf = (float*)d_ws;
    int* wsi = (int*)((float*)d_ws + 2 * B_DIM);
    (void)in_sizes; (void)n_in; (void)out_size; (void)ws_size;

    // init via graph-capturable memsets (drops one kernel launch):
    // Cacc/tsAcc = 0.0f; firstAcc = 0x7F7F7F7F (min-identity, clamped in fin)
    hipMemsetAsync(wsf, 0, 2 * B_DIM * sizeof(float), stream);
    hipMemsetAsync(wsi, 0x7F, B_DIM * sizeof(int), stream);
    lif_kernel<<<(B_DIM / 64) * (NSEG / 2), 128, 0, stream>>>(I, out, wsf, wsf + B_DIM, wsi);
    fin_kernel<<<(B_DIM + 255) / 256, 256, 0, stream>>>(wsf, wsf + B_DIM, wsi, out);
}

// Round 9
// 134.006 us; speedup vs baseline: 1.0935x; 1.0935x over previous
//
#include <hip/hip_runtime.h>

#define B_DIM 4096
#define L_DIM 4096
#define SEGLEN 256
#define NSEG (L_DIM / SEGLEN)   // 16
#define WARM 512                // coupling window (proven exact)
#define CHUNK 64                // time steps per chunk
#define LROW 64                 // LDS floats per row: LINEAR (global_load_lds dest)

typedef __attribute__((ext_vector_type(4))) float f32x4;  // native vec for nt-store

// Exact IEEE step (proven absmax 0): q = RN(u/20) via Markstein, compare off
// the dependent chain: u' = sp_prev ? I' : ((u - q) + I')
#define LIF_CORE(IIN)                         \
    float q0 = u * cdiv;                      \
    float rr = fmaf(-20.0f, q0, u);           \
    float q  = fmaf(rr, cdiv, q0);            \
    float a  = u - q;                        \
    float b  = a + (IIN);                     \
    u = sp ? (IIN) : b;                       \
    sp = (u >= 1.0f);

#define WARM_STEP(IIN) { LIF_CORE(IIN) }

#define FULL_STEP(IIN, SOUT)                  \
    {                                         \
        LIF_CORE(IIN)                         \
        float sf = sp ? 1.0f : 0.0f;          \
        cnt += sf;                            \
        seen = fmaxf(seen, sf);               \
        accS += cnt;                          \
        accF += seen;                         \
        (SOUT) = sf;                          \
    }

typedef const __attribute__((address_space(1))) void g_void;
typedef __attribute__((address_space(3))) void l_void;
__device__ __forceinline__ void gll16(const float* src, float* ldsbase) {
    // async global->LDS, 16B/lane; LDS dest = wave-uniform base + lane*16B
    __builtin_amdgcn_global_load_lds((g_void*)src, (l_void*)ldsbase, 16, 0, 0);
}

// ROUND 9 = round-6 kernel (best measured: 52us, FETCH 90MB, WRITE exactly
// 66.3MB, 0 conflicts) + ONE change: spike stores are NON-TEMPORAL
// (round-8 intent; fixed to use a native ext_vector_type for the builtin).
//
// Rationale (invariant across R0-R7): dur ~= hbm_bytes / ~3 TB/s for every
// schedule tried -> effective-BW-bound, so shrink hbm_bytes. Output (66MB,
// never re-read) currently allocates in L2/L3 and evicts the 64MB input;
// R0's FETCH=58MB < input proves L3 retains input ACROSS dispatches when
// pressure allows. nt stores (no-allocate/stream) leave L3 to the input ->
// warm re-reads + steady-state re-runs stop hitting HBM.
//
// Everything else identical to round 6:
//  - fully decoupled waves, zero barriers; wave = 64 rows x one 256-step seg
//  - gll linear LDS dest + both-sides swizzle (block (k-r)&15 / (j+lane)&15)
//  - depth-1 prefetch, counted vmcnt(16) (stores youngest) / vmcnt(0) warm
//  - spikes overwrite the just-consumed input buffer (same-wave in-order LDS)
__global__ __launch_bounds__(128, 1) void lif_kernel(const float* __restrict__ I,
                                                     float* __restrict__ out,
                                                     float* __restrict__ Cacc,
                                                     float* __restrict__ tsAcc,
                                                     int* __restrict__ firstAcc) {
    __shared__ __align__(16) float lds[2][2][64 * LROW];  // [wave][dbuf] 64KB
    const int wid = threadIdx.x >> 6;
    const int lane = threadIdx.x & 63;
    float* buf0 = &lds[wid][0][0];
    float* buf1 = &lds[wid][1][0];

    // 512 blocks: rowgroup = b>>3; segpair = b&7; wave seg = 2*pair + wid
    const int rowBase = (blockIdx.x >> 3) * 64;
    const int seg = ((blockIdx.x & 7) << 1) + wid;
    const int t0 = seg * SEGLEN;
    const int start = (t0 > WARM) ? (t0 - WARM) : 0;
    const int nwarmCh = (t0 - start) / CHUNK;     // 0, 4, or 8
    const int nch = nwarmCh + SEGLEN / CHUNK;     // 4, 8, or 12

    const int srow = lane >> 4, scol = lane & 15;
    const float* gbase = I + (size_t)rowBase * L_DIM + start;

    const int row = rowBase + lane;
    float u = 0.f, cnt = 0.f, seen = 0.f, accS = 0.f, accF = 0.f;
    bool sp = false;
    const float cdiv = 0.05f;  // RN(1/20)
    float4 R[16];

#define GLL_CHUNK(CC, DST)                                                  \
    {                                                                       \
        const float* gsrc = gbase + (size_t)(CC) * CHUNK;                   \
        _Pragma("unroll")                                                   \
        for (int p = 0; p < 16; ++p) {                                      \
            const int r = 4 * p + srow;                                     \
            gll16(gsrc + (size_t)r * L_DIM + (((scol - r) & 15) << 2),      \
                  (DST) + p * 256);                                         \
        }                                                                   \
    }

#define READ_R(SRC)                                                         \
    {                                                                       \
        _Pragma("unroll")                                                   \
        for (int j = 0; j < 16; ++j)                                        \
            R[j] = *(const float4*)&(SRC)[lane * LROW + (((j + lane) & 15) << 2)]; \
    }

    // prologue: chunk 0 -> LDS -> R (one exposed latency, once)
    GLL_CHUNK(0, buf0)
    asm volatile("s_waitcnt vmcnt(0)" ::: "memory");
    __builtin_amdgcn_sched_barrier(0);
    READ_R(buf0)

    for (int c = 0; c < nch; ++c) {
        float* bufc = (c & 1) ? buf1 : buf0;
        float* bufn = (c & 1) ? buf0 : buf1;

        // 1. async-stage chunk c+1 (no registers consumed)
        if (c + 1 < nch) GLL_CHUNK(c + 1, bufn)
        __builtin_amdgcn_sched_barrier(0);

        // 2. compute chunk c from R
        if (c < nwarmCh) {
#pragma unroll
            for (int j = 0; j < 16; ++j) {
                float4 iv = R[j];
                WARM_STEP(iv.x) WARM_STEP(iv.y) WARM_STEP(iv.z) WARM_STEP(iv.w)
            }
        } else {
            // spikes overwrite bufc (input c fully consumed into R; same-wave
            // in-order LDS). Swizzled slots k=(j+lane)&15.
#pragma unroll
            for (int j = 0; j < 16; ++j) {
                float4 iv = R[j];
                float4 sv;
                FULL_STEP(iv.x, sv.x) FULL_STEP(iv.y, sv.y)
                FULL_STEP(iv.z, sv.z) FULL_STEP(iv.w, sv.w)
                *(float4*)&bufc[lane * LROW + (((j + lane) & 15) << 2)] = sv;
            }
            // 3. coalesced spike store: linear LDS read -> swizzled global
            //    col. NON-TEMPORAL: output is never re-read; nt keeps it from
            //    evicting the L3-resident input (the one change vs round 6).
            f32x4 S[16];
#pragma unroll
            for (int p = 0; p < 16; ++p)
                S[p] = *(const f32x4*)&bufc[p * 256 + lane * 4];
            float* og = out + (size_t)rowBase * L_DIM + t0 +
                        (size_t)(c - nwarmCh) * CHUNK;
#pragma unroll
            for (int p = 0; p < 16; ++p) {
                const int r = 4 * p + srow;
                __builtin_nontemporal_store(
                    S[p], (f32x4*)(og + (size_t)r * L_DIM + (((scol - r) & 15) << 2)));
            }
        }

        // 4. counted drain + next-chunk register load
        if (c + 1 < nch) {
            if (c >= nwarmCh) {
                // retain this iter's 16 stores; drain gll(c+1) + older stores
                asm volatile("s_waitcnt vmcnt(16)" ::: "memory");
            } else {
                asm volatile("s_waitcnt vmcnt(0)" ::: "memory");
            }
            __builtin_amdgcn_sched_barrier(0);
            READ_R(bufn)
        }
    }

    // per-segment partials (exact integers < 2^24 -> float atomics exact)
    if (cnt > 0.f) {
        const int firstLocal = (int)((float)SEGLEN - accF);
        atomicMin(&firstAcc[row], t0 + firstLocal);
    }
    atomicAdd(&Cacc[row], cnt);
    atomicAdd(&tsAcc[row], fmaf((float)(t0 + SEGLEN), cnt, -accS));
#undef GLL_CHUNK
#undef READ_R
}

__global__ __launch_bounds__(256) void fin_kernel(const float* __restrict__ Cacc,
                                                  const float* __restrict__ tsAcc,
                                                  const int* __restrict__ firstAcc,
                                                  float* __restrict__ out) {
    int r = blockIdx.x * 256 + threadIdx.x;
    if (r < B_DIM) {
        // firstAcc initialized to 0x7F7F7F7F by memset; clamp restores the
        // exact no-spike identity L_DIM.
        int f = firstAcc[r];
        out[(size_t)B_DIM * L_DIM + r] = (float)(f > L_DIM ? L_DIM : f);
        out[(size_t)B_DIM * L_DIM + B_DIM + r] = tsAcc[r] / (Cacc[r] + 1e-6f);
    }
}

extern "C" void kernel_launch(void* const* d_in, const int* in_sizes, int n_in,
                              void* d_out, int out_size, void* d_ws, size_t ws_size,
                              hipStream_t stream) {
    const float* I = (const float*)d_in[0];
    float* out = (float*)d_out;
    float* wsf = (float*)d_ws;
    int* wsi = (int*)((float*)d_ws + 2 * B_DIM);
    (void)in_sizes; (void)n_in; (void)out_size; (void)ws_size;

    // init via graph-capturable memsets:
    // Cacc/tsAcc = 0.0f; firstAcc = 0x7F7F7F7F (min-identity, clamped in fin)
    (void)hipMemsetAsync(wsf, 0, 2 * B_DIM * sizeof(float), stream);
    (void)hipMemsetAsync(wsi, 0x7F, B_DIM * sizeof(int), stream);
    lif_kernel<<<(B_DIM / 64) * (NSEG / 2), 128, 0, stream>>>(I, out, wsf, wsf + B_DIM, wsi);
    fin_kernel<<<(B_DIM + 255) / 256, 256, 0, stream>>>(wsf, wsf + B_DIM, wsi, out);
}